// Round 18
// baseline (318.912 us; speedup 1.0000x reference)
//
#include <hip/hip_runtime.h>
#include <math.h>

// ---------------- problem constants (fixed by setup_inputs) ----------------
constexpr int D   = 64;
constexpr int H   = 8;
constexpr int HD  = 8;
constexpr int NL  = 3;
constexpr int FFNx= 256;
constexpr int Bb  = 4;
constexpr int Ss  = 2048;
constexpr int NT  = Bb * Ss;        // 8192 tokens
constexpr int MAXC= 1024;
constexpr int MCL = 16;

// attention: q-tile = 256 (4 queries/lane), key chunk = 128 (paired waves
// of 64 keys). tasks per bh: sum_{t=0..7} 2(t+1) = 72; canonical task index
// = t*(t+1) + s  (s in 0..2t+1). Enumeration for dispatch is s-outer.
constexpr int TPB  = 72;             // tasks per (b,h)
constexpr int BPB  = 36;             // blocks per (b,h) (2 tasks per block)
constexpr int PBSZ = 2304;           // floats per partial: l(256) + o(2048)

// ---------------- workspace layout (float elements) ----------------
constexpr size_t WX  = 0;                        // [NT*D]
constexpr size_t WQ  = 524288;                   // [NT*D]
constexpr size_t WKV = 2621440;                  // [32*2048*16] interleaved K|V
constexpr size_t WPB = 4194304;                  // [32*TPB*PBSZ] attn partials
constexpr size_t WL1 = 9764864;                  // [NT]
constexpr size_t WEM = WL1 + NT;                 // [NT] int
constexpr size_t WINV= WEM + NT;                 // [Bb*MAXC*MCL] int inverse map
constexpr size_t WCT = WINV + Bb*MAXC*MCL;       // [Ss*4]
constexpr size_t WST = WCT + Ss*4;               // [Ss*4]

constexpr float LOG2E = 1.4426950408889634f;

typedef float v2f  __attribute__((ext_vector_type(2)));
typedef float f16v __attribute__((ext_vector_type(16)));
using ckv_t = const __attribute__((address_space(4))) f16v*;

__device__ __forceinline__ float rdlane(float v, int l) {
    return __builtin_bit_cast(float, __builtin_amdgcn_readlane(__builtin_bit_cast(int, v), l));
}

// ---------------- init: copy x -> X, build rope tables ----------------
__global__ void k_init(const float* __restrict__ x, float* __restrict__ X,
                       float* __restrict__ ct, float* __restrict__ st) {
    int i = blockIdx.x * blockDim.x + threadIdx.x;
    constexpr int N4 = NT * D / 4;
    if (i < N4) ((float4*)X)[i] = ((const float4*)x)[i];
    if (i < Ss * 4) {
        int s = i >> 2, f = i & 3;
        const float fr[4] = {1.0f, 0.1f, 0.01f, 0.001f};
        float ang = (float)s * fr[f];
        ct[i] = cosf(ang);
        st[i] = sinf(ang);
    }
}

// ---------------- rmsnorm + QKV + rope (layer 0 only) ----------------
__global__ __launch_bounds__(256) void k_qkv(
    const float* __restrict__ X, const float* __restrict__ Wq,
    const float* __restrict__ Wk, const float* __restrict__ Wv,
    const float* __restrict__ g1, const float* __restrict__ ct,
    const float* __restrict__ st, float* __restrict__ Q,
    float* __restrict__ KV) {
    __shared__ float wq_s[D*D], wk_s[D*D], wv_s[D*D];
    __shared__ float g_s[D];
    int tid = threadIdx.x;
    for (int i = tid; i < D*D; i += 256) {
        wq_s[i] = Wq[i]; wk_s[i] = Wk[i]; wv_s[i] = Wv[i];
    }
    if (tid < D) g_s[tid] = g1[tid];
    __syncthreads();
    int w = tid >> 6, d = tid & 63;
    int t0 = blockIdx.x * 16;
    for (int it = 0; it < 4; ++it) {
        int t = t0 + it*4 + w;
        float xv = X[t*D + d];
        float ss = xv * xv;
        #pragma unroll
        for (int off = 32; off; off >>= 1) ss += __shfl_xor(ss, off);
        float r = 1.0f / sqrtf(ss * (1.0f/D) + 1e-6f);
        float h = xv * g_s[d] * r;
        float aq = 0.f, ak = 0.f, av = 0.f;
        #pragma unroll
        for (int j = 0; j < D; ++j) {
            float hj = rdlane(h, j);
            aq += hj * wq_s[j*D + d];
            ak += hj * wk_s[j*D + d];
            av += hj * wv_s[j*D + d];
        }
        int s  = t & (Ss - 1);
        int e  = d & 7;
        int fi = e & 3;
        float c  = ct[s*4 + fi];
        float sn = st[s*4 + fi];
        float pq = __shfl_xor(aq, 4);
        float pk = __shfl_xor(ak, 4);
        float rq, rk;
        if (e < 4) { rq = aq*c - pq*sn; rk = ak*c - pk*sn; }
        else       { rq = pq*sn + aq*c; rk = pk*sn + ak*c; }
        Q[t*D + d] = rq;
        int bq = t >> 11;
        int hh = d >> 3;
        float* kvp = KV + ((((size_t)(bq*H + hh))*Ss + s) << 4);
        kvp[e]     = rk;
        kvp[8 + e] = av;
    }
}

// ---------------- attention 64-key loop: 4 queries/lane, s_load KV --------
template<int DIAG>
__device__ __forceinline__ void attn_loop4(
    ckv_t kvs, int L, int rel0,
    const v2f* __restrict__ qp0, const v2f* __restrict__ qp1,
    v2f& l0, v2f& l1, v2f* __restrict__ o0, v2f* __restrict__ o1) {
    #pragma unroll 4
    for (int j = 0; j < 64; ++j) {
        f16v kv = kvs[j];
        v2f a1;
        a1  = qp1[0] * (v2f){kv[0], kv[0]};
        a1 += qp1[1] * (v2f){kv[1], kv[1]};
        a1 += qp1[2] * (v2f){kv[2], kv[2]};
        a1 += qp1[3] * (v2f){kv[3], kv[3]};
        a1 += qp1[4] * (v2f){kv[4], kv[4]};
        a1 += qp1[5] * (v2f){kv[5], kv[5]};
        a1 += qp1[6] * (v2f){kv[6], kv[6]};
        a1 += qp1[7] * (v2f){kv[7], kv[7]};
        if (DIAG == 2) {
            int rel = rel0 + j;
            if (rel > L)      a1.x = -1e30f;
            if (rel > L + 64) a1.y = -1e30f;
        }
        v2f p1;
        p1.x = __builtin_amdgcn_exp2f(a1.x);
        p1.y = __builtin_amdgcn_exp2f(a1.y);
        l1 += p1;
        o1[0] += p1 * (v2f){kv[8],  kv[8]};
        o1[1] += p1 * (v2f){kv[9],  kv[9]};
        o1[2] += p1 * (v2f){kv[10], kv[10]};
        o1[3] += p1 * (v2f){kv[11], kv[11]};
        o1[4] += p1 * (v2f){kv[12], kv[12]};
        o1[5] += p1 * (v2f){kv[13], kv[13]};
        o1[6] += p1 * (v2f){kv[14], kv[14]};
        o1[7] += p1 * (v2f){kv[15], kv[15]};
        if (DIAG != 2) {
            v2f a0;
            a0  = qp0[0] * (v2f){kv[0], kv[0]};
            a0 += qp0[1] * (v2f){kv[1], kv[1]};
            a0 += qp0[2] * (v2f){kv[2], kv[2]};
            a0 += qp0[3] * (v2f){kv[3], kv[3]};
            a0 += qp0[4] * (v2f){kv[4], kv[4]};
            a0 += qp0[5] * (v2f){kv[5], kv[5]};
            a0 += qp0[6] * (v2f){kv[6], kv[6]};
            a0 += qp0[7] * (v2f){kv[7], kv[7]};
            if (DIAG == 1) {
                int rel = rel0 + j;
                if (rel > L)      a0.x = -1e30f;
                if (rel > L + 64) a0.y = -1e30f;
            }
            v2f p0;
            p0.x = __builtin_amdgcn_exp2f(a0.x);
            p0.y = __builtin_amdgcn_exp2f(a0.y);
            l0 += p0;
            o0[0] += p0 * (v2f){kv[8],  kv[8]};
            o0[1] += p0 * (v2f){kv[9],  kv[9]};
            o0[2] += p0 * (v2f){kv[10], kv[10]};
            o0[3] += p0 * (v2f){kv[11], kv[11]};
            o0[4] += p0 * (v2f){kv[12], kv[12]};
            o0[5] += p0 * (v2f){kv[13], kv[13]};
            o0[6] += p0 * (v2f){kv[14], kv[14]};
            o0[7] += p0 * (v2f){kv[15], kv[15]};
        }
    }
}

// ---------------- causal attention: 4 q/lane, paired-wave, XCD-pinned -----
__global__ __launch_bounds__(256) void k_attn2(
    const float* __restrict__ Qg, const float* __restrict__ KV,
    float* __restrict__ PB) {
    __shared__ float comb[2][PBSZ];
    int xcd  = blockIdx.x & 7;
    int slot = blockIdx.x >> 3;
    int bhg  = slot / BPB;
    int blk  = slot - bhg * BPB;
    int bh   = bhg * 8 + xcd;
    int wvu  = __builtin_amdgcn_readfirstlane(threadIdx.x >> 6); // uniform
    int pair = wvu >> 1;
    int half = wvu & 1;
    int widb = blk * 2 + pair;                 // task 0..71 (s-outer order)
    int L = threadIdx.x & 63;
    int rem = widb;
    int s = 0;
    while (rem >= 8 - (s >> 1)) { rem -= 8 - (s >> 1); ++s; }
    int t = (s >> 1) + rem;
    int b = bh >> 3, h = bh & 7;
    int qmin = t * 256;
    int k0 = s * 128 + half * 64;

    const float SC = 0.35355339059327373f * LOG2E;   // 1/sqrt(8) * log2(e)
    const float* qp = Qg + ((size_t)(b*Ss + qmin + L))*D + h*HD;
    float4 qa0 = *(const float4*)(qp);
    float4 qb0 = *(const float4*)(qp + 4);
    float4 qa1 = *(const float4*)(qp + 64*D);
    float4 qb1 = *(const float4*)(qp + 64*D + 4);
    float4 qa2 = *(const float4*)(qp + 128*D);
    float4 qb2 = *(const float4*)(qp + 128*D + 4);
    float4 qa3 = *(const float4*)(qp + 192*D);
    float4 qb3 = *(const float4*)(qp + 192*D + 4);
    v2f qp0[8], qp1[8];
    qp0[0] = (v2f){qa0.x*SC, qa1.x*SC};  qp1[0] = (v2f){qa2.x*SC, qa3.x*SC};
    qp0[1] = (v2f){qa0.y*SC, qa1.y*SC};  qp1[1] = (v2f){qa2.y*SC, qa3.y*SC};
    qp0[2] = (v2f){qa0.z*SC, qa1.z*SC};  qp1[2] = (v2f){qa2.z*SC, qa3.z*SC};
    qp0[3] = (v2f){qa0.w*SC, qa1.w*SC};  qp1[3] = (v2f){qa2.w*SC, qa3.w*SC};
    qp0[4] = (v2f){qb0.x*SC, qb1.x*SC};  qp1[4] = (v2f){qb2.x*SC, qb3.x*SC};
    qp0[5] = (v2f){qb0.y*SC, qb1.y*SC};  qp1[5] = (v2f){qb2.y*SC, qb3.y*SC};
    qp0[6] = (v2f){qb0.z*SC, qb1.z*SC};  qp1[6] = (v2f){qb2.z*SC, qb3.z*SC};
    qp0[7] = (v2f){qb0.w*SC, qb1.w*SC};  qp1[7] = (v2f){qb2.w*SC, qb3.w*SC};

    v2f l0 = (v2f){0.f, 0.f}, l1 = (v2f){0.f, 0.f};
    v2f o0[8], o1[8];
    #pragma unroll
    for (int e = 0; e < 8; ++e) { o0[e] = (v2f){0.f, 0.f}; o1[e] = (v2f){0.f, 0.f}; }

    ckv_t kvs = (ckv_t)(unsigned long long)(KV + (((size_t)bh*Ss + k0) << 4));
    if (s == 2*t)          attn_loop4<1>(kvs, L, half*64, qp0, qp1, l0, l1, o0, o1);
    else if (s == 2*t + 1) attn_loop4<2>(kvs, L, half*64, qp0, qp1, l0, l1, o0, o1);
    else                   attn_loop4<0>(kvs, L, half*64, qp0, qp1, l0, l1, o0, o1);

    if (half == 1) {
        comb[pair][L]       = l0.x;
        comb[pair][64 + L]  = l0.y;
        comb[pair][128 + L] = l1.x;
        comb[pair][192 + L] = l1.y;
        #pragma unroll
        for (int e = 0; e < 8; ++e) {
            comb[pair][256 + e*256 + L]       = o0[e].x;
            comb[pair][256 + e*256 + 64 + L]  = o0[e].y;
            comb[pair][256 + e*256 + 128 + L] = o1[e].x;
            comb[pair][256 + e*256 + 192 + L] = o1[e].y;
        }
    }
    __syncthreads();
    if (half == 0) {
        int pbidx = t*(t+1) + s;
        float* pb = PB + ((size_t)bh * TPB + pbidx) * PBSZ;
        pb[L]       = l0.x + comb[pair][L];
        pb[64 + L]  = l0.y + comb[pair][64 + L];
        pb[128 + L] = l1.x + comb[pair][128 + L];
        pb[192 + L] = l1.y + comb[pair][192 + L];
        #pragma unroll
        for (int e = 0; e < 8; ++e) {
            pb[256 + e*256 + L]       = o0[e].x + comb[pair][256 + e*256 + L];
            pb[256 + e*256 + 64 + L]  = o0[e].y + comb[pair][256 + e*256 + 64 + L];
            pb[256 + e*256 + 128 + L] = o1[e].x + comb[pair][256 + e*256 + 128 + L];
            pb[256 + e*256 + 192 + L] = o1[e].y + comb[pair][256 + e*256 + 192 + L];
        }
    }
}

// ---------------- fused combine + X+=O@Wo + FFN (+head / +next-layer QKV) --
// grid 512 blocks x 16 tokens. Aliased LDS: the qkv weight stage reuses the
// wo_s/oT/xt/h2t/ult/red regions, all dead after FFN phase 2.
template<bool HEAD, bool NEXTQ>
__global__ __launch_bounds__(256) void k_cffn(
    const float* __restrict__ PB, float* __restrict__ X,
    const float* __restrict__ Wo, const float* __restrict__ g2,
    const float* __restrict__ W1, const float* __restrict__ W2,
    const float* __restrict__ Wh, const float* __restrict__ bhp,
    float* __restrict__ logit1, int* __restrict__ em,
    const float* __restrict__ Wqn, const float* __restrict__ Wkn,
    const float* __restrict__ Wvn, const float* __restrict__ g1n,
    const float* __restrict__ ct, const float* __restrict__ st,
    float* __restrict__ Q, float* __restrict__ KV) {
    __shared__ __align__(16) float smem[16992];
    float* wo_s = smem;                                  // [4096]
    auto  oT   = (float(*)[65])(smem + 4096);            // [16][65]
    auto  xt   = (float(*)[65])(smem + 5136);            // [16][65]
    auto  h2t  = (float(*)[20])(smem + 6176);            // [64][20]
    auto  part = (float(*)[16])(smem + 7456);            // [16][16]
    float* g_s = smem + 7712;                            // [64]
    auto  ult  = (float(*)[20])(smem + 7776);            // [256][20]
    auto  red  = (float(*)[16][64])(smem + 12896);       // [4][16][64]
    int tid = threadIdx.x;
    int gb  = blockIdx.x;
    int b    = gb >> 7;
    int tile = gb & 127;
    int t    = tile >> 4;
    int sq   = (tile & 15) << 4;           // first qs of this block in q-tile
    int tok0 = b*Ss + t*256 + sq;          // first global token
    for (int i = tid; i < D*D; i += 256) wo_s[i] = Wo[i];
    if (tid < D) g_s[tid] = g2[tid];

    {   // combine: 16 qs x 8 heads, e-range split over 2 threads
        int h  = tid >> 5;
        int ql = (tid >> 1) & 15;
        int eh = tid & 1;
        int qs = sq + ql;
        int bh = b*8 + h;
        int nch = 2*(t+1);
        float Lx = 0.f;
        float O[4] = {0,0,0,0};
        for (int s3 = 0; s3 < nch; ++s3) {
            int idx = t*(t+1) + s3;
            const float* pb = PB + (size_t)(bh*TPB + idx) * PBSZ;
            Lx += pb[qs];
            #pragma unroll
            for (int e = 0; e < 4; ++e) O[e] += pb[256 + (eh*4 + e)*256 + qs];
        }
        float inv = 1.0f / Lx;
        #pragma unroll
        for (int e = 0; e < 4; ++e) oT[ql][h*8 + eh*4 + e] = O[e] * inv;
    }
    __syncthreads();
    {   // xt = X + oT @ Wo
        int d = tid & 63, wv = tid >> 6;
        #pragma unroll
        for (int k = 0; k < 4; ++k) {
            int tt = wv*4 + k;
            float a = 0.f;
            #pragma unroll
            for (int j = 0; j < D; ++j) a += oT[tt][j] * wo_s[j*D + d];
            xt[tt][d] = X[(size_t)(tok0 + tt)*D + d] + a;
        }
    }
    __syncthreads();
    int tk = tid >> 4, li = tid & 15;
    float x0 = xt[tk][li];
    float x1 = xt[tk][li + 16];
    float x2 = xt[tk][li + 32];
    float x3 = xt[tk][li + 48];
    part[tk][li] = x0*x0 + x1*x1 + x2*x2 + x3*x3;
    __syncthreads();
    if (tid < 16) {
        float s = 0.f;
        #pragma unroll
        for (int i = 0; i < 16; ++i) s += part[tid][i];
        part[tid][0] = 1.0f / sqrtf(s * (1.0f/D) + 1e-6f);
    }
    __syncthreads();
    float r = part[tk][0];
    h2t[li][tk]      = x0 * g_s[li]      * r;
    h2t[li + 16][tk] = x1 * g_s[li + 16] * r;
    h2t[li + 32][tk] = x2 * g_s[li + 32] * r;
    h2t[li + 48][tk] = x3 * g_s[li + 48] * r;
    __syncthreads();
    {   // phase 1: U = gelu(h2 @ W1) -> LDS
        int f = tid;
        v2f acc2[8];
        #pragma unroll
        for (int i = 0; i < 8; ++i) acc2[i] = (v2f){0.f, 0.f};
        for (int j = 0; j < D; ++j) {
            float wv = W1[j*FFNx + f];
            v2f wv2 = (v2f){wv, wv};
            const float4* hp = (const float4*)&h2t[j][0];
            float4 a0 = hp[0], a1 = hp[1], a2 = hp[2], a3 = hp[3];
            const v2f* a0v = (const v2f*)&a0;
            const v2f* a1v = (const v2f*)&a1;
            const v2f* a2v = (const v2f*)&a2;
            const v2f* a3v = (const v2f*)&a3;
            acc2[0] += a0v[0]*wv2;  acc2[1] += a0v[1]*wv2;
            acc2[2] += a1v[0]*wv2;  acc2[3] += a1v[1]*wv2;
            acc2[4] += a2v[0]*wv2;  acc2[5] += a2v[1]*wv2;
            acc2[6] += a3v[0]*wv2;  acc2[7] += a3v[1]*wv2;
        }
        #pragma unroll
        for (int i = 0; i < 8; ++i) {
            float ua = acc2[i].x;
            float ub = acc2[i].y;
            ua = 0.5f * ua * (1.0f + erff(ua * 0.70710678118654752f));
            ub = 0.5f * ub * (1.0f + erff(ub * 0.70710678118654752f));
            ult[f][2*i]     = ua;
            ult[f][2*i + 1] = ub;
        }
    }
    __syncthreads();
    // phase 2: X = xt + U @ W2 (+ head); keep xf in registers for NEXTQ
    float xfr[4];
    int d2 = tid & 63, fp = tid >> 6;
    {
        v2f acc2[8];
        #pragma unroll
        for (int i = 0; i < 8; ++i) acc2[i] = (v2f){0.f, 0.f};
        for (int fo = 0; fo < 64; ++fo) {
            int f = fp*64 + fo;
            float wv = W2[f*D + d2];
            v2f wv2 = (v2f){wv, wv};
            const float4* up = (const float4*)&ult[f][0];
            float4 u0 = up[0], u1 = up[1], u2 = up[2], u3 = up[3];
            const v2f* u0v = (const v2f*)&u0;
            const v2f* u1v = (const v2f*)&u1;
            const v2f* u2v = (const v2f*)&u2;
            const v2f* u3v = (const v2f*)&u3;
            acc2[0] += u0v[0]*wv2;  acc2[1] += u0v[1]*wv2;
            acc2[2] += u1v[0]*wv2;  acc2[3] += u1v[1]*wv2;
            acc2[4] += u2v[0]*wv2;  acc2[5] += u2v[1]*wv2;
            acc2[6] += u3v[0]*wv2;  acc2[7] += u3v[1]*wv2;
        }
        #pragma unroll
        for (int i = 0; i < 8; ++i) {
            red[fp][2*i][d2]     = acc2[i].x;
            red[fp][2*i + 1][d2] = acc2[i].y;
        }
        __syncthreads();
        int tk2 = tid >> 6;
        #pragma unroll
        for (int k = 0; k < 4; ++k) {
            int tt = tk2 + k*4;
            float sum = red[0][tt][d2] + red[1][tt][d2] + red[2][tt][d2] + red[3][tt][d2];
            float xf = xt[tt][d2] + sum;
            xfr[k] = xf;
            X[(size_t)(tok0 + tt)*D + d2] = xf;
            if (HEAD) {
                float p0 = xf * Wh[d2*2];
                float p1 = xf * Wh[d2*2 + 1];
                #pragma unroll
                for (int off = 32; off; off >>= 1) {
                    p0 += __shfl_xor(p0, off);
                    p1 += __shfl_xor(p1, off);
                }
                if (d2 == 0) {
                    float l0 = p0 + bhp[0], l1 = p1 + bhp[1];
                    em[tok0 + tt] = (l0 > l1) ? 1 : 0;
                    logit1[tok0 + tt] = l1;
                }
            }
        }
    }
    if (NEXTQ) {
        __syncthreads();                           // all reads of smem done
        float* wq_s = smem;                        // alias [4096]
        float* wk_s = smem + 4096;                 // alias [4096]
        float* wv_s = smem + 8192;                 // alias [4096]
        float* g1_s = smem + 12288;                // alias [64]
        for (int i = tid; i < D*D; i += 256) {
            wq_s[i] = Wqn[i]; wk_s[i] = Wkn[i]; wv_s[i] = Wvn[i];
        }
        if (tid < D) g1_s[tid] = g1n[tid];
        __syncthreads();
        int wvi = tid >> 6, d = tid & 63;
        #pragma unroll
        for (int k = 0; k < 4; ++k) {
            int tglob = tok0 + wvi + k*4;
            float xv = xfr[k];
            float ss = xv * xv;
            #pragma unroll
            for (int off = 32; off; off >>= 1) ss += __shfl_xor(ss, off);
            float rq_ = 1.0f / sqrtf(ss * (1.0f/D) + 1e-6f);
            float h = xv * g1_s[d] * rq_;
            float aq = 0.f, ak = 0.f, av = 0.f;
            #pragma unroll
            for (int j = 0; j < D; ++j) {
                float hj = rdlane(h, j);
                aq += hj * wq_s[j*D + d];
                ak += hj * wk_s[j*D + d];
                av += hj * wv_s[j*D + d];
            }
            int s  = tglob & (Ss - 1);
            int e  = d & 7;
            int fi = e & 3;
            float c  = ct[s*4 + fi];
            float sn = st[s*4 + fi];
            float pq = __shfl_xor(aq, 4);
            float pk = __shfl_xor(ak, 4);
            float rq, rk;
            if (e < 4) { rq = aq*c - pq*sn; rk = ak*c - pk*sn; }
            else       { rq = pq*sn + aq*c; rk = pk*sn + ak*c; }
            Q[(size_t)tglob*D + d] = rq;
            int bq = tglob >> 11;
            int hh = d >> 3;
            float* kvp = KV + ((((size_t)(bq*H + hh))*Ss + s) << 4);
            kvp[e]     = rk;
            kvp[8 + e] = av;
        }
    }
}

// ---------------- scan (blocks 0..3) + reg mean (block 4) ----------------
__global__ __launch_bounds__(256) void k_scanreg(
    const int* __restrict__ em, int* __restrict__ inv,
    const float* __restrict__ logit1, float* __restrict__ outreg) {
    __shared__ int ssum[256], smax[256];
    __shared__ int sany, stot;
    int tid = threadIdx.x;
    if (blockIdx.x == Bb) {
        __shared__ float redf[256];
        float s = 0.f;
        for (int i = tid; i < NT; i += 256) s += logit1[i];
        redf[tid] = s;
        __syncthreads();
        for (int off = 128; off; off >>= 1) {
            if (tid < off) redf[tid] += redf[tid + off];
            __syncthreads();
        }
        if (tid == 0) *outreg = redf[0] * (1.0f / NT);
        return;
    }
    int b = blockIdx.x;
    int* invb = inv + b * (MAXC*MCL);
    for (int i = tid; i < MAXC*MCL; i += 256) invb[i] = -1;
    __syncthreads();
    const int* e = em + b*Ss;
    int base = tid * 8;
    int loc[8];
    int lsum = 0, lor = 0;
    #pragma unroll
    for (int i = 0; i < 8; ++i) { loc[i] = e[base + i]; lsum += loc[i]; lor |= loc[i]; }
    ssum[tid] = lor;
    __syncthreads();
    if (tid == 0) { int a = 0; for (int i = 0; i < 256; ++i) a |= ssum[i]; sany = a; }
    __syncthreads();
    int any = sany;
    __syncthreads();
    if (!any && tid == 255) { loc[7] = 1; lsum = 1; }
    int prev = (tid == 0) ? 1 : e[base - 1];
    if (!any && tid) prev = 0;
    int mk[8];
    int lmax = -1;
    #pragma unroll
    for (int i = 0; i < 8; ++i) {
        int pe = (i == 0) ? prev : loc[i - 1];
        if (i == 7 && !any && tid == 255) pe = e[base + 6];
        mk[i] = pe ? (base + i) : -1;
        lmax = max(lmax, mk[i]);
    }
    ssum[tid] = lsum; smax[tid] = lmax;
    __syncthreads();
    if (tid == 0) {
        int rs = 0, rm = -1;
        for (int i = 0; i < 256; ++i) {
            int ts = ssum[i], tm = smax[i];
            ssum[i] = rs; smax[i] = rm;
            rs += ts; rm = max(rm, tm);
        }
        stot = rs;
    }
    __syncthreads();
    int run = ssum[tid], rmax = smax[tid], tot = stot;
    #pragma unroll
    for (int i = 0; i < 8; ++i) {
        int s = base + i;
        rmax = max(rmax, mk[i]);
        int chunk = run;
        run += loc[i];
        int pos = s - rmax;
        bool valid = (chunk < tot) && (chunk < MAXC) && (pos < MCL);
        if (valid) invb[chunk * MCL + pos] = b*Ss + s;   // global token id
    }
}

// ---------------- gather epilogue: write out (vectors + ids) --------------
__global__ __launch_bounds__(256) void k_out(
    const float* __restrict__ X, const float* __restrict__ pad,
    const int* __restrict__ xids, const int* __restrict__ padid,
    const int* __restrict__ inv, float* __restrict__ out) {
    int i = blockIdx.x * blockDim.x + threadIdx.x;
    constexpr int NV4 = Bb * MAXC * MCL * D / 4;   // 1048576
    constexpr int NI4 = Bb * MAXC * MCL / 4;       // 16384
    if (i < NV4) {
        int slot = i >> 4;
        int d4 = i & 15;
        int t = inv[slot];
        float4 v = (t >= 0) ? ((const float4*)X)[t*16 + d4]
                            : ((const float4*)pad)[d4];
        ((float4*)out)[i] = v;
    } else if (i < NV4 + NI4) {
        int j = i - NV4;
        float pv = (float)(*padid);
        int base = j * 4;
        int t0_ = inv[base], t1_ = inv[base+1], t2_ = inv[base+2], t3_ = inv[base+3];
        float4 v;
        v.x = (t0_ >= 0) ? (float)xids[t0_] : pv;
        v.y = (t1_ >= 0) ? (float)xids[t1_] : pv;
        v.z = (t2_ >= 0) ? (float)xids[t2_] : pv;
        v.w = (t3_ >= 0) ? (float)xids[t3_] : pv;
        ((float4*)out)[i] = v;
    }
}

// ---------------- launch ----------------
extern "C" void kernel_launch(void* const* d_in, const int* in_sizes, int n_in,
                              void* d_out, int out_size, void* d_ws, size_t ws_size,
                              hipStream_t stream) {
    const float* x    = (const float*)d_in[0];
    const float* pad  = (const float*)d_in[1];
    const int*   xids = (const int*)  d_in[2];
    const int*   padid= (const int*)  d_in[3];
    const float* Wq   = (const float*)d_in[4];
    const float* Wk   = (const float*)d_in[5];
    const float* Wv   = (const float*)d_in[6];
    const float* Wo   = (const float*)d_in[7];
    const float* ln1  = (const float*)d_in[8];
    const float* ln2  = (const float*)d_in[9];
    const float* W1   = (const float*)d_in[10];
    const float* W2   = (const float*)d_in[11];
    const float* Wh   = (const float*)d_in[12];
    const float* bh   = (const float*)d_in[13];
    float* out = (float*)d_out;
    float* ws  = (float*)d_ws;

    float* X  = ws + WX;
    float* Qb = ws + WQ;
    float* KVb= ws + WKV;
    float* PBb= ws + WPB;
    float* L1b= ws + WL1;
    int*   EMb= (int*)(ws + WEM);
    int*   INVb=(int*)(ws + WINV);
    float* ct = ws + WCT;
    float* st = ws + WST;

    k_init<<<2048, 256, 0, stream>>>(x, X, ct, st);
    k_qkv <<<512, 256, 0, stream>>>(X, Wq, Wk, Wv, ln1, ct, st, Qb, KVb);
    for (int l = 0; l < NL; ++l) {
        k_attn2<<<32*BPB, 256, 0, stream>>>(Qb, KVb, PBb);
        if (l == NL - 1)
            k_cffn<true , false><<<512, 256, 0, stream>>>(
                PBb, X, Wo + l*D*D, ln2 + l*D, W1 + l*D*FFNx, W2 + l*FFNx*D,
                Wh, bh, L1b, EMb,
                nullptr, nullptr, nullptr, nullptr, ct, st, Qb, KVb);
        else
            k_cffn<false, true ><<<512, 256, 0, stream>>>(
                PBb, X, Wo + l*D*D, ln2 + l*D, W1 + l*D*FFNx, W2 + l*FFNx*D,
                nullptr, nullptr, nullptr, nullptr,
                Wq + (l+1)*D*D, Wk + (l+1)*D*D, Wv + (l+1)*D*D, ln1 + (l+1)*D,
                ct, st, Qb, KVb);
    }
    k_scanreg<<<Bb + 1, 256, 0, stream>>>(EMb, INVb, L1b,
                                          out + (size_t)Bb*MAXC*MCL*D + Bb*MAXC*MCL);
    k_out <<<(Bb*MAXC*MCL*D/4 + Bb*MAXC*MCL/4 + 255)/256, 256, 0, stream>>>(
        X, pad, xids, padid, INVb, out);
}

// Round 19
// 247.721 us; speedup vs baseline: 1.2874x; 1.2874x over previous
//
#include <hip/hip_runtime.h>
#include <math.h>

// ---------------- problem constants (fixed by setup_inputs) ----------------
constexpr int D   = 64;
constexpr int H   = 8;
constexpr int HD  = 8;
constexpr int NL  = 3;
constexpr int FFNx= 256;
constexpr int Bb  = 4;
constexpr int Ss  = 2048;
constexpr int NT  = Bb * Ss;        // 8192 tokens
constexpr int MAXC= 1024;
constexpr int MCL = 16;

// attention: q-tile = 256 (4 queries/lane), key chunk = 128 (paired waves
// of 64 keys). tasks per bh: sum_{t=0..7} 2(t+1) = 72; canonical task index
// = t*(t+1) + s  (s in 0..2t+1). Enumeration for dispatch is s-outer.
constexpr int TPB  = 72;             // tasks per (b,h)
constexpr int BPB  = 36;             // blocks per (b,h) (2 tasks per block)
constexpr int PBSZ = 2304;           // floats per partial: l(256) + o(2048)

// ---------------- workspace layout (float elements) ----------------
constexpr size_t WX  = 0;                        // [NT*D]
constexpr size_t WQ  = 524288;                   // [NT*D]
constexpr size_t WKV = 2621440;                  // [32*2048*16] interleaved K|V
constexpr size_t WPB = 4194304;                  // [32*TPB*PBSZ] attn partials
constexpr size_t WL1 = 9764864;                  // [NT]
constexpr size_t WEM = WL1 + NT;                 // [NT] int
constexpr size_t WINV= WEM + NT;                 // [Bb*MAXC*MCL] int inverse map
constexpr size_t WCT = WINV + Bb*MAXC*MCL;       // [Ss*4]
constexpr size_t WST = WCT + Ss*4;               // [Ss*4]

constexpr float LOG2E = 1.4426950408889634f;

typedef float v2f  __attribute__((ext_vector_type(2)));
typedef float f16v __attribute__((ext_vector_type(16)));
using ckv_t = const __attribute__((address_space(4))) f16v*;

__device__ __forceinline__ float rdlane(float v, int l) {
    return __builtin_bit_cast(float, __builtin_amdgcn_readlane(__builtin_bit_cast(int, v), l));
}

// ---------------- init: copy x -> X, build rope tables ----------------
__global__ void k_init(const float* __restrict__ x, float* __restrict__ X,
                       float* __restrict__ ct, float* __restrict__ st) {
    int i = blockIdx.x * blockDim.x + threadIdx.x;
    constexpr int N4 = NT * D / 4;
    if (i < N4) ((float4*)X)[i] = ((const float4*)x)[i];
    if (i < Ss * 4) {
        int s = i >> 2, f = i & 3;
        const float fr[4] = {1.0f, 0.1f, 0.01f, 0.001f};
        float ang = (float)s * fr[f];
        ct[i] = cosf(ang);
        st[i] = sinf(ang);
    }
}

// ---------------- rmsnorm + QKV + rope (wave-per-token, readlane bcast) ----
__global__ __launch_bounds__(256) void k_qkv(
    const float* __restrict__ X, const float* __restrict__ Wq,
    const float* __restrict__ Wk, const float* __restrict__ Wv,
    const float* __restrict__ g1, const float* __restrict__ ct,
    const float* __restrict__ st, float* __restrict__ Q,
    float* __restrict__ KV) {
    __shared__ float wq_s[D*D], wk_s[D*D], wv_s[D*D];
    __shared__ float g_s[D];
    int tid = threadIdx.x;
    for (int i = tid; i < D*D; i += 256) {
        wq_s[i] = Wq[i]; wk_s[i] = Wk[i]; wv_s[i] = Wv[i];
    }
    if (tid < D) g_s[tid] = g1[tid];
    __syncthreads();
    int w = tid >> 6, d = tid & 63;
    int t0 = blockIdx.x * 16;
    for (int it = 0; it < 4; ++it) {
        int t = t0 + it*4 + w;
        float xv = X[t*D + d];
        float ss = xv * xv;
        #pragma unroll
        for (int off = 32; off; off >>= 1) ss += __shfl_xor(ss, off);
        float r = 1.0f / sqrtf(ss * (1.0f/D) + 1e-6f);
        float h = xv * g_s[d] * r;
        float aq = 0.f, ak = 0.f, av = 0.f;
        #pragma unroll
        for (int j = 0; j < D; ++j) {
            float hj = rdlane(h, j);
            aq += hj * wq_s[j*D + d];
            ak += hj * wk_s[j*D + d];
            av += hj * wv_s[j*D + d];
        }
        int s  = t & (Ss - 1);
        int e  = d & 7;
        int fi = e & 3;
        float c  = ct[s*4 + fi];
        float sn = st[s*4 + fi];
        float pq = __shfl_xor(aq, 4);
        float pk = __shfl_xor(ak, 4);
        float rq, rk;
        if (e < 4) { rq = aq*c - pq*sn; rk = ak*c - pk*sn; }
        else       { rq = pq*sn + aq*c; rk = pk*sn + ak*c; }
        Q[t*D + d] = rq;
        int bq = t >> 11;
        int hh = d >> 3;
        float* kvp = KV + ((((size_t)(bq*H + hh))*Ss + s) << 4);
        kvp[e]     = rk;
        kvp[8 + e] = av;
    }
}

// ---------------- attention 64-key loop: 4 queries/lane, s_load KV --------
template<int DIAG>
__device__ __forceinline__ void attn_loop4(
    ckv_t kvs, int L, int rel0,
    const v2f* __restrict__ qp0, const v2f* __restrict__ qp1,
    v2f& l0, v2f& l1, v2f* __restrict__ o0, v2f* __restrict__ o1) {
    #pragma unroll 4
    for (int j = 0; j < 64; ++j) {
        f16v kv = kvs[j];
        v2f a1;
        a1  = qp1[0] * (v2f){kv[0], kv[0]};
        a1 += qp1[1] * (v2f){kv[1], kv[1]};
        a1 += qp1[2] * (v2f){kv[2], kv[2]};
        a1 += qp1[3] * (v2f){kv[3], kv[3]};
        a1 += qp1[4] * (v2f){kv[4], kv[4]};
        a1 += qp1[5] * (v2f){kv[5], kv[5]};
        a1 += qp1[6] * (v2f){kv[6], kv[6]};
        a1 += qp1[7] * (v2f){kv[7], kv[7]};
        if (DIAG == 2) {
            int rel = rel0 + j;
            if (rel > L)      a1.x = -1e30f;
            if (rel > L + 64) a1.y = -1e30f;
        }
        v2f p1;
        p1.x = __builtin_amdgcn_exp2f(a1.x);
        p1.y = __builtin_amdgcn_exp2f(a1.y);
        l1 += p1;
        o1[0] += p1 * (v2f){kv[8],  kv[8]};
        o1[1] += p1 * (v2f){kv[9],  kv[9]};
        o1[2] += p1 * (v2f){kv[10], kv[10]};
        o1[3] += p1 * (v2f){kv[11], kv[11]};
        o1[4] += p1 * (v2f){kv[12], kv[12]};
        o1[5] += p1 * (v2f){kv[13], kv[13]};
        o1[6] += p1 * (v2f){kv[14], kv[14]};
        o1[7] += p1 * (v2f){kv[15], kv[15]};
        if (DIAG != 2) {
            v2f a0;
            a0  = qp0[0] * (v2f){kv[0], kv[0]};
            a0 += qp0[1] * (v2f){kv[1], kv[1]};
            a0 += qp0[2] * (v2f){kv[2], kv[2]};
            a0 += qp0[3] * (v2f){kv[3], kv[3]};
            a0 += qp0[4] * (v2f){kv[4], kv[4]};
            a0 += qp0[5] * (v2f){kv[5], kv[5]};
            a0 += qp0[6] * (v2f){kv[6], kv[6]};
            a0 += qp0[7] * (v2f){kv[7], kv[7]};
            if (DIAG == 1) {
                int rel = rel0 + j;
                if (rel > L)      a0.x = -1e30f;
                if (rel > L + 64) a0.y = -1e30f;
            }
            v2f p0;
            p0.x = __builtin_amdgcn_exp2f(a0.x);
            p0.y = __builtin_amdgcn_exp2f(a0.y);
            l0 += p0;
            o0[0] += p0 * (v2f){kv[8],  kv[8]};
            o0[1] += p0 * (v2f){kv[9],  kv[9]};
            o0[2] += p0 * (v2f){kv[10], kv[10]};
            o0[3] += p0 * (v2f){kv[11], kv[11]};
            o0[4] += p0 * (v2f){kv[12], kv[12]};
            o0[5] += p0 * (v2f){kv[13], kv[13]};
            o0[6] += p0 * (v2f){kv[14], kv[14]};
            o0[7] += p0 * (v2f){kv[15], kv[15]};
        }
    }
}

// ---------------- causal attention: 4 q/lane, paired-wave, XCD-pinned -----
__global__ __launch_bounds__(256) void k_attn2(
    const float* __restrict__ Qg, const float* __restrict__ KV,
    float* __restrict__ PB) {
    __shared__ float comb[2][PBSZ];
    int xcd  = blockIdx.x & 7;
    int slot = blockIdx.x >> 3;
    int bhg  = slot / BPB;
    int blk  = slot - bhg * BPB;
    int bh   = bhg * 8 + xcd;
    int wvu  = __builtin_amdgcn_readfirstlane(threadIdx.x >> 6); // uniform
    int pair = wvu >> 1;
    int half = wvu & 1;
    int widb = blk * 2 + pair;                 // task 0..71 (s-outer order)
    int L = threadIdx.x & 63;
    int rem = widb;
    int s = 0;
    while (rem >= 8 - (s >> 1)) { rem -= 8 - (s >> 1); ++s; }
    int t = (s >> 1) + rem;
    int b = bh >> 3, h = bh & 7;
    int qmin = t * 256;
    int k0 = s * 128 + half * 64;

    const float SC = 0.35355339059327373f * LOG2E;   // 1/sqrt(8) * log2(e)
    const float* qp = Qg + ((size_t)(b*Ss + qmin + L))*D + h*HD;
    float4 qa0 = *(const float4*)(qp);
    float4 qb0 = *(const float4*)(qp + 4);
    float4 qa1 = *(const float4*)(qp + 64*D);
    float4 qb1 = *(const float4*)(qp + 64*D + 4);
    float4 qa2 = *(const float4*)(qp + 128*D);
    float4 qb2 = *(const float4*)(qp + 128*D + 4);
    float4 qa3 = *(const float4*)(qp + 192*D);
    float4 qb3 = *(const float4*)(qp + 192*D + 4);
    v2f qp0[8], qp1[8];
    qp0[0] = (v2f){qa0.x*SC, qa1.x*SC};  qp1[0] = (v2f){qa2.x*SC, qa3.x*SC};
    qp0[1] = (v2f){qa0.y*SC, qa1.y*SC};  qp1[1] = (v2f){qa2.y*SC, qa3.y*SC};
    qp0[2] = (v2f){qa0.z*SC, qa1.z*SC};  qp1[2] = (v2f){qa2.z*SC, qa3.z*SC};
    qp0[3] = (v2f){qa0.w*SC, qa1.w*SC};  qp1[3] = (v2f){qa2.w*SC, qa3.w*SC};
    qp0[4] = (v2f){qb0.x*SC, qb1.x*SC};  qp1[4] = (v2f){qb2.x*SC, qb3.x*SC};
    qp0[5] = (v2f){qb0.y*SC, qb1.y*SC};  qp1[5] = (v2f){qb2.y*SC, qb3.y*SC};
    qp0[6] = (v2f){qb0.z*SC, qb1.z*SC};  qp1[6] = (v2f){qb2.z*SC, qb3.z*SC};
    qp0[7] = (v2f){qb0.w*SC, qb1.w*SC};  qp1[7] = (v2f){qb2.w*SC, qb3.w*SC};

    v2f l0 = (v2f){0.f, 0.f}, l1 = (v2f){0.f, 0.f};
    v2f o0[8], o1[8];
    #pragma unroll
    for (int e = 0; e < 8; ++e) { o0[e] = (v2f){0.f, 0.f}; o1[e] = (v2f){0.f, 0.f}; }

    ckv_t kvs = (ckv_t)(unsigned long long)(KV + (((size_t)bh*Ss + k0) << 4));
    if (s == 2*t)          attn_loop4<1>(kvs, L, half*64, qp0, qp1, l0, l1, o0, o1);
    else if (s == 2*t + 1) attn_loop4<2>(kvs, L, half*64, qp0, qp1, l0, l1, o0, o1);
    else                   attn_loop4<0>(kvs, L, half*64, qp0, qp1, l0, l1, o0, o1);

    if (half == 1) {
        comb[pair][L]       = l0.x;
        comb[pair][64 + L]  = l0.y;
        comb[pair][128 + L] = l1.x;
        comb[pair][192 + L] = l1.y;
        #pragma unroll
        for (int e = 0; e < 8; ++e) {
            comb[pair][256 + e*256 + L]       = o0[e].x;
            comb[pair][256 + e*256 + 64 + L]  = o0[e].y;
            comb[pair][256 + e*256 + 128 + L] = o1[e].x;
            comb[pair][256 + e*256 + 192 + L] = o1[e].y;
        }
    }
    __syncthreads();
    if (half == 0) {
        int pbidx = t*(t+1) + s;
        float* pb = PB + ((size_t)bh * TPB + pbidx) * PBSZ;
        pb[L]       = l0.x + comb[pair][L];
        pb[64 + L]  = l0.y + comb[pair][64 + L];
        pb[128 + L] = l1.x + comb[pair][128 + L];
        pb[192 + L] = l1.y + comb[pair][192 + L];
        #pragma unroll
        for (int e = 0; e < 8; ++e) {
            pb[256 + e*256 + L]       = o0[e].x + comb[pair][256 + e*256 + L];
            pb[256 + e*256 + 64 + L]  = o0[e].y + comb[pair][256 + e*256 + 64 + L];
            pb[256 + e*256 + 128 + L] = o1[e].x + comb[pair][256 + e*256 + 128 + L];
            pb[256 + e*256 + 192 + L] = o1[e].y + comb[pair][256 + e*256 + 192 + L];
        }
    }
}

// ---------------- fused combine + X+=O@Wo + FFN (+ head) ------------------
// grid 512 blocks x 16 tokens. Bitwise-identical to r16's k_combo->k_ffn
// chain: same per-element summation orders; X kept in LDS between stages.
template<bool HEAD>
__global__ __launch_bounds__(256) void k_cffn(
    const float* __restrict__ PB, float* __restrict__ X,
    const float* __restrict__ Wo, const float* __restrict__ g2,
    const float* __restrict__ W1, const float* __restrict__ W2,
    const float* __restrict__ Wh, const float* __restrict__ bhp,
    float* __restrict__ logit1, int* __restrict__ em) {
    __shared__ float wo_s[D*D];
    __shared__ float oT[16][65];
    __shared__ float xt[16][65];
    __shared__ __align__(16) float h2t[64][20];
    __shared__ float part[16][16];
    __shared__ float g_s[D];
    __shared__ __align__(16) float ult[FFNx][20];
    __shared__ float red[4][16][D];
    int tid = threadIdx.x;
    int gb  = blockIdx.x;
    int b    = gb >> 7;
    int tile = gb & 127;
    int t    = tile >> 4;
    int sq   = (tile & 15) << 4;           // first qs of this block in q-tile
    int tok0 = b*Ss + t*256 + sq;          // first global token
    for (int i = tid; i < D*D; i += 256) wo_s[i] = Wo[i];
    if (tid < D) g_s[tid] = g2[tid];

    {   // combine: 16 qs x 8 heads, e-range split over 2 threads
        int h  = tid >> 5;
        int ql = (tid >> 1) & 15;
        int eh = tid & 1;
        int qs = sq + ql;
        int bh = b*8 + h;
        int nch = 2*(t+1);
        float Lx = 0.f;
        float O[4] = {0,0,0,0};
        for (int s3 = 0; s3 < nch; ++s3) {
            int idx = t*(t+1) + s3;
            const float* pb = PB + (size_t)(bh*TPB + idx) * PBSZ;
            Lx += pb[qs];
            #pragma unroll
            for (int e = 0; e < 4; ++e) O[e] += pb[256 + (eh*4 + e)*256 + qs];
        }
        float inv = 1.0f / Lx;
        #pragma unroll
        for (int e = 0; e < 4; ++e) oT[ql][h*8 + eh*4 + e] = O[e] * inv;
    }
    __syncthreads();
    {   // xt = X + oT @ Wo
        int d = tid & 63, wv = tid >> 6;
        #pragma unroll
        for (int k = 0; k < 4; ++k) {
            int tt = wv*4 + k;
            float a = 0.f;
            #pragma unroll
            for (int j = 0; j < D; ++j) a += oT[tt][j] * wo_s[j*D + d];
            xt[tt][d] = X[(size_t)(tok0 + tt)*D + d] + a;
        }
    }
    __syncthreads();
    int tk = tid >> 4, li = tid & 15;
    float x0 = xt[tk][li];
    float x1 = xt[tk][li + 16];
    float x2 = xt[tk][li + 32];
    float x3 = xt[tk][li + 48];
    part[tk][li] = x0*x0 + x1*x1 + x2*x2 + x3*x3;
    __syncthreads();
    if (tid < 16) {
        float s = 0.f;
        #pragma unroll
        for (int i = 0; i < 16; ++i) s += part[tid][i];
        part[tid][0] = 1.0f / sqrtf(s * (1.0f/D) + 1e-6f);
    }
    __syncthreads();
    float r = part[tk][0];
    h2t[li][tk]      = x0 * g_s[li]      * r;
    h2t[li + 16][tk] = x1 * g_s[li + 16] * r;
    h2t[li + 32][tk] = x2 * g_s[li + 32] * r;
    h2t[li + 48][tk] = x3 * g_s[li + 48] * r;
    __syncthreads();
    {   // phase 1: U = gelu(h2 @ W1) -> LDS
        int f = tid;
        v2f acc2[8];
        #pragma unroll
        for (int i = 0; i < 8; ++i) acc2[i] = (v2f){0.f, 0.f};
        for (int j = 0; j < D; ++j) {
            float wv = W1[j*FFNx + f];
            v2f wv2 = (v2f){wv, wv};
            const float4* hp = (const float4*)&h2t[j][0];
            float4 a0 = hp[0], a1 = hp[1], a2 = hp[2], a3 = hp[3];
            const v2f* a0v = (const v2f*)&a0;
            const v2f* a1v = (const v2f*)&a1;
            const v2f* a2v = (const v2f*)&a2;
            const v2f* a3v = (const v2f*)&a3;
            acc2[0] += a0v[0]*wv2;  acc2[1] += a0v[1]*wv2;
            acc2[2] += a1v[0]*wv2;  acc2[3] += a1v[1]*wv2;
            acc2[4] += a2v[0]*wv2;  acc2[5] += a2v[1]*wv2;
            acc2[6] += a3v[0]*wv2;  acc2[7] += a3v[1]*wv2;
        }
        #pragma unroll
        for (int i = 0; i < 8; ++i) {
            float ua = acc2[i].x;
            float ub = acc2[i].y;
            ua = 0.5f * ua * (1.0f + erff(ua * 0.70710678118654752f));
            ub = 0.5f * ub * (1.0f + erff(ub * 0.70710678118654752f));
            ult[f][2*i]     = ua;
            ult[f][2*i + 1] = ub;
        }
    }
    __syncthreads();
    {   // phase 2: X = xt + U @ W2 (+ head on last layer)
        int d = tid & 63, fp = tid >> 6;
        v2f acc2[8];
        #pragma unroll
        for (int i = 0; i < 8; ++i) acc2[i] = (v2f){0.f, 0.f};
        for (int fo = 0; fo < 64; ++fo) {
            int f = fp*64 + fo;
            float wv = W2[f*D + d];
            v2f wv2 = (v2f){wv, wv};
            const float4* up = (const float4*)&ult[f][0];
            float4 u0 = up[0], u1 = up[1], u2 = up[2], u3 = up[3];
            const v2f* u0v = (const v2f*)&u0;
            const v2f* u1v = (const v2f*)&u1;
            const v2f* u2v = (const v2f*)&u2;
            const v2f* u3v = (const v2f*)&u3;
            acc2[0] += u0v[0]*wv2;  acc2[1] += u0v[1]*wv2;
            acc2[2] += u1v[0]*wv2;  acc2[3] += u1v[1]*wv2;
            acc2[4] += u2v[0]*wv2;  acc2[5] += u2v[1]*wv2;
            acc2[6] += u3v[0]*wv2;  acc2[7] += u3v[1]*wv2;
        }
        #pragma unroll
        for (int i = 0; i < 8; ++i) {
            red[fp][2*i][d]     = acc2[i].x;
            red[fp][2*i + 1][d] = acc2[i].y;
        }
        __syncthreads();
        int tk2 = tid >> 6;
        #pragma unroll
        for (int k = 0; k < 4; ++k) {
            int tt = tk2 + k*4;
            float sum = red[0][tt][d] + red[1][tt][d] + red[2][tt][d] + red[3][tt][d];
            float xf = xt[tt][d] + sum;
            X[(size_t)(tok0 + tt)*D + d] = xf;
            if (HEAD) {
                float p0 = xf * Wh[d*2];
                float p1 = xf * Wh[d*2 + 1];
                #pragma unroll
                for (int off = 32; off; off >>= 1) {
                    p0 += __shfl_xor(p0, off);
                    p1 += __shfl_xor(p1, off);
                }
                if (d == 0) {
                    float l0 = p0 + bhp[0], l1 = p1 + bhp[1];
                    em[tok0 + tt] = (l0 > l1) ? 1 : 0;
                    logit1[tok0 + tt] = l1;
                }
            }
        }
    }
}

// ---------------- scan (blocks 0..3) + reg mean (block 4) ----------------
__global__ __launch_bounds__(256) void k_scanreg(
    const int* __restrict__ em, int* __restrict__ inv,
    const float* __restrict__ logit1, float* __restrict__ outreg) {
    __shared__ int ssum[256], smax[256];
    __shared__ int sany, stot;
    int tid = threadIdx.x;
    if (blockIdx.x == Bb) {
        __shared__ float redf[256];
        float s = 0.f;
        for (int i = tid; i < NT; i += 256) s += logit1[i];
        redf[tid] = s;
        __syncthreads();
        for (int off = 128; off; off >>= 1) {
            if (tid < off) redf[tid] += redf[tid + off];
            __syncthreads();
        }
        if (tid == 0) *outreg = redf[0] * (1.0f / NT);
        return;
    }
    int b = blockIdx.x;
    int* invb = inv + b * (MAXC*MCL);
    for (int i = tid; i < MAXC*MCL; i += 256) invb[i] = -1;
    __syncthreads();
    const int* e = em + b*Ss;
    int base = tid * 8;
    int loc[8];
    int lsum = 0, lor = 0;
    #pragma unroll
    for (int i = 0; i < 8; ++i) { loc[i] = e[base + i]; lsum += loc[i]; lor |= loc[i]; }
    ssum[tid] = lor;
    __syncthreads();
    if (tid == 0) { int a = 0; for (int i = 0; i < 256; ++i) a |= ssum[i]; sany = a; }
    __syncthreads();
    int any = sany;
    __syncthreads();
    if (!any && tid == 255) { loc[7] = 1; lsum = 1; }
    int prev = (tid == 0) ? 1 : e[base - 1];
    if (!any && tid) prev = 0;
    int mk[8];
    int lmax = -1;
    #pragma unroll
    for (int i = 0; i < 8; ++i) {
        int pe = (i == 0) ? prev : loc[i - 1];
        if (i == 7 && !any && tid == 255) pe = e[base + 6];
        mk[i] = pe ? (base + i) : -1;
        lmax = max(lmax, mk[i]);
    }
    ssum[tid] = lsum; smax[tid] = lmax;
    __syncthreads();
    if (tid == 0) {
        int rs = 0, rm = -1;
        for (int i = 0; i < 256; ++i) {
            int ts = ssum[i], tm = smax[i];
            ssum[i] = rs; smax[i] = rm;
            rs += ts; rm = max(rm, tm);
        }
        stot = rs;
    }
    __syncthreads();
    int run = ssum[tid], rmax = smax[tid], tot = stot;
    #pragma unroll
    for (int i = 0; i < 8; ++i) {
        int s = base + i;
        rmax = max(rmax, mk[i]);
        int chunk = run;
        run += loc[i];
        int pos = s - rmax;
        bool valid = (chunk < tot) && (chunk < MAXC) && (pos < MCL);
        if (valid) invb[chunk * MCL + pos] = b*Ss + s;   // global token id
    }
}

// ---------------- gather epilogue: write out (vectors + ids) --------------
__global__ __launch_bounds__(256) void k_out(
    const float* __restrict__ X, const float* __restrict__ pad,
    const int* __restrict__ xids, const int* __restrict__ padid,
    const int* __restrict__ inv, float* __restrict__ out) {
    int i = blockIdx.x * blockDim.x + threadIdx.x;
    constexpr int NV4 = Bb * MAXC * MCL * D / 4;   // 1048576
    constexpr int NI4 = Bb * MAXC * MCL / 4;       // 16384
    if (i < NV4) {
        int slot = i >> 4;
        int d4 = i & 15;
        int t = inv[slot];
        float4 v = (t >= 0) ? ((const float4*)X)[t*16 + d4]
                            : ((const float4*)pad)[d4];
        ((float4*)out)[i] = v;
    } else if (i < NV4 + NI4) {
        int j = i - NV4;
        float pv = (float)(*padid);
        int base = j * 4;
        int t0_ = inv[base], t1_ = inv[base+1], t2_ = inv[base+2], t3_ = inv[base+3];
        float4 v;
        v.x = (t0_ >= 0) ? (float)xids[t0_] : pv;
        v.y = (t1_ >= 0) ? (float)xids[t1_] : pv;
        v.z = (t2_ >= 0) ? (float)xids[t2_] : pv;
        v.w = (t3_ >= 0) ? (float)xids[t3_] : pv;
        ((float4*)out)[i] = v;
    }
}

// ---------------- launch ----------------
extern "C" void kernel_launch(void* const* d_in, const int* in_sizes, int n_in,
                              void* d_out, int out_size, void* d_ws, size_t ws_size,
                              hipStream_t stream) {
    const float* x    = (const float*)d_in[0];
    const float* pad  = (const float*)d_in[1];
    const int*   xids = (const int*)  d_in[2];
    const int*   padid= (const int*)  d_in[3];
    const float* Wq   = (const float*)d_in[4];
    const float* Wk   = (const float*)d_in[5];
    const float* Wv   = (const float*)d_in[6];
    const float* Wo   = (const float*)d_in[7];
    const float* ln1  = (const float*)d_in[8];
    const float* ln2  = (const float*)d_in[9];
    const float* W1   = (const float*)d_in[10];
    const float* W2   = (const float*)d_in[11];
    const float* Wh   = (const float*)d_in[12];
    const float* bh   = (const float*)d_in[13];
    float* out = (float*)d_out;
    float* ws  = (float*)d_ws;

    float* X  = ws + WX;
    float* Qb = ws + WQ;
    float* KVb= ws + WKV;
    float* PBb= ws + WPB;
    float* L1b= ws + WL1;
    int*   EMb= (int*)(ws + WEM);
    int*   INVb=(int*)(ws + WINV);
    float* ct = ws + WCT;
    float* st = ws + WST;

    k_init<<<2048, 256, 0, stream>>>(x, X, ct, st);
    for (int l = 0; l < NL; ++l) {
        k_qkv <<<512, 256, 0, stream>>>(X, Wq + l*D*D, Wk + l*D*D, Wv + l*D*D,
                                        ln1 + l*D, ct, st, Qb, KVb);
        k_attn2<<<32*BPB, 256, 0, stream>>>(Qb, KVb, PBb);
        if (l == NL - 1)
            k_cffn<true ><<<512, 256, 0, stream>>>(PBb, X, Wo + l*D*D, ln2 + l*D,
                                                   W1 + l*D*FFNx, W2 + l*FFNx*D,
                                                   Wh, bh, L1b, EMb);
        else
            k_cffn<false><<<512, 256, 0, stream>>>(PBb, X, Wo + l*D*D, ln2 + l*D,
                                                   W1 + l*D*FFNx, W2 + l*FFNx*D,
                                                   nullptr, nullptr, nullptr, nullptr);
    }
    k_scanreg<<<Bb + 1, 256, 0, stream>>>(EMb, INVb, L1b,
                                          out + (size_t)Bb*MAXC*MCL*D + Bb*MAXC*MCL);
    k_out <<<(Bb*MAXC*MCL*D/4 + Bb*MAXC*MCL/4 + 255)/256, 256, 0, stream>>>(
        X, pad, xids, padid, INVb, out);
}